// Round 17
// baseline (175.982 us; speedup 1.0000x reference)
//
#include <hip/hip_runtime.h>

#define SEQ     2048
#define DMODEL  1024
#define NHEADS  16
#define DKH     64
#define BATCH   4

typedef __bf16 bf16x8 __attribute__((ext_vector_type(8)));
typedef float  f32x4  __attribute__((ext_vector_type(4)));
typedef float  f32x16 __attribute__((ext_vector_type(16)));

static __device__ __forceinline__ unsigned short f2bf(float x) {
  unsigned int u = __float_as_uint(x);
  u += 0x7fffu + ((u >> 16) & 1u);
  return (unsigned short)(u >> 16);
}
static __device__ __forceinline__ float bf2f(unsigned short b) {
  return __uint_as_float(((unsigned int)b) << 16);
}
static __device__ __forceinline__ void gload_lds16(const void* g, void* lds) {
  __builtin_amdgcn_global_load_lds((const __attribute__((address_space(1))) void*)g,
                                   (__attribute__((address_space(3))) void*)lds,
                                   16, 0, 0);
}
static __device__ __forceinline__ f32x4 mfma16(bf16x8 a, bf16x8 b, f32x4 c) {
  return __builtin_amdgcn_mfma_f32_16x16x32_bf16(a, b, c, 0, 0, 0);
}
static __device__ __forceinline__ f32x16 mfma32(bf16x8 a, bf16x8 b, f32x16 c) {
  return __builtin_amdgcn_mfma_f32_32x32x16_bf16(a, b, c, 0, 0, 0);
}
static __device__ __forceinline__ unsigned cvtpk_bf16(float lo, float hi) {
  unsigned r;
  asm("v_cvt_pk_bf16_f32 %0, %1, %2" : "=v"(r) : "v"(lo), "v"(hi));
  return r;
}
static __device__ __forceinline__ bf16x8 pack4(unsigned a, unsigned b,
                                               unsigned c, unsigned d) {
  union { unsigned u[4]; bf16x8 v; } t;
  t.u[0] = a; t.u[1] = b; t.u[2] = c; t.u[3] = d;
  return t.v;
}

// ---------------- fp32 -> bf16 cast ----------------
__global__ void cast_kernel(const float* __restrict__ src,
                            unsigned short* __restrict__ dst, int n4) {
  int i = blockIdx.x * 256 + threadIdx.x;
  if (i >= n4) return;
  float4 v = ((const float4*)src)[i];
  ushort4 o;
  o.x = f2bf(v.x); o.y = f2bf(v.y); o.z = f2bf(v.z); o.w = f2bf(v.w);
  ((ushort4*)dst)[i] = o;
}

// 4 weight matrices in one launch (blockIdx.y selects)
__global__ void cast4_kernel(const float* __restrict__ s0, const float* __restrict__ s1,
                             const float* __restrict__ s2, const float* __restrict__ s3,
                             unsigned short* __restrict__ d0, unsigned short* __restrict__ d1,
                             unsigned short* __restrict__ d2, unsigned short* __restrict__ d3,
                             int n4) {
  int i = blockIdx.x * 256 + threadIdx.x;
  if (i >= n4) return;
  const float* s = (blockIdx.y == 0) ? s0 : (blockIdx.y == 1) ? s1 : (blockIdx.y == 2) ? s2 : s3;
  unsigned short* d = (blockIdx.y == 0) ? d0 : (blockIdx.y == 1) ? d1 : (blockIdx.y == 2) ? d2 : d3;
  float4 v = ((const float4*)s)[i];
  ushort4 o;
  o.x = f2bf(v.x); o.y = f2bf(v.y); o.z = f2bf(v.z); o.w = f2bf(v.w);
  ((ushort4*)d)[i] = o;
}

// ---------------- GEMM (frozen round-16): 128x128, BK=64, dbuf vmcnt(8),
// 32x32x16 MFMA; V^T via LDS-transposed coalesced stores ----------------
template<int EPI>
__global__ __launch_bounds__(256)
void gemm_bt(const unsigned short* __restrict__ A,
             const unsigned short* __restrict__ W0,
             const unsigned short* __restrict__ W1,
             const unsigned short* __restrict__ W2,
             unsigned short* __restrict__ O0,
             unsigned short* __restrict__ O1,
             unsigned short* __restrict__ O2,
             float* __restrict__ Of)
{
  __shared__ unsigned short smem[4][128*64];   // [0..1]=A dbuf, [2..3]=B dbuf (64 KiB)
  const int tid = threadIdx.x;
  const int lane = tid & 63, w = tid >> 6;
  const int wm = w >> 1, wn = w & 1;
  const int l31 = lane & 31, lg2 = lane >> 5;

  const int NWG = (EPI == 0) ? 1536 : 512;
  const int CPX = NWG / 8;
  const int lgid = (blockIdx.x & 7) * CPX + (blockIdx.x >> 3);
  const int n0 = (lgid & 7) * 128;
  const int m0 = ((lgid >> 3) & 63) * 128;
  const int z  = (EPI == 0) ? (lgid >> 9) : 0;
  const unsigned short* Bw = (EPI == 0)
      ? ((z == 0) ? W0 : ((z == 1) ? W1 : W2)) : W0;

  f32x16 acc[2][2];
  #pragma unroll
  for (int a = 0; a < 2; ++a)
    #pragma unroll
    for (int b = 0; b < 2; ++b)
      #pragma unroll
      for (int r = 0; r < 16; ++r)
        acc[a][b][r] = 0.f;

  auto STAGE = [&](int buf, int t) {
    const int k0 = t * 64;
    #pragma unroll
    for (int it = 0; it < 4; ++it) {
      int c = it*4 + w;
      int off16 = c*64 + lane;
      int r = off16 >> 3, p = off16 & 7;
      int s = p ^ (r & 7);
      gload_lds16(A  + (size_t)(m0 + r)*DMODEL + k0 + s*8, (char*)smem[buf]     + c*1024);
      gload_lds16(Bw + (size_t)(n0 + r)*DMODEL + k0 + s*8, (char*)smem[2 + buf] + c*1024);
    }
  };

  const int NT = DMODEL / 64;
  STAGE(0, 0);
  STAGE(1, 1);

  for (int t = 0; t < NT; ++t) {
    const int cur = t & 1;
    if (t == NT - 1) asm volatile("s_waitcnt vmcnt(0)" ::: "memory");
    else             asm volatile("s_waitcnt vmcnt(8)" ::: "memory");
    __builtin_amdgcn_s_barrier();
    __builtin_amdgcn_sched_barrier(0);

    #pragma unroll
    for (int ks = 0; ks < 4; ++ks) {       // K-slices of 16 within BK=64
      bf16x8 af[2], bg[2];
      #pragma unroll
      for (int bi = 0; bi < 2; ++bi) {
        int row = wm*64 + bi*32 + l31;
        int sp = (ks*2 + lg2) ^ (row & 7);
        af[bi] = *(const bf16x8*)((const char*)smem[cur] + row*128 + sp*16);
      }
      #pragma unroll
      for (int bj = 0; bj < 2; ++bj) {
        int row = wn*64 + bj*32 + l31;
        int sp = (ks*2 + lg2) ^ (row & 7);
        bg[bj] = *(const bf16x8*)((const char*)smem[2 + cur] + row*128 + sp*16);
      }
      __builtin_amdgcn_s_setprio(1);
      #pragma unroll
      for (int bi = 0; bi < 2; ++bi)
        #pragma unroll
        for (int bj = 0; bj < 2; ++bj)
          acc[bi][bj] = mfma32(af[bi], bg[bj], acc[bi][bj]);
      __builtin_amdgcn_s_setprio(0);
    }

    __builtin_amdgcn_sched_barrier(0);
    __builtin_amdgcn_s_barrier();
    __builtin_amdgcn_sched_barrier(0);
    if (t + 2 < NT) STAGE(cur, t + 2);
  }

  // C/D layout (m74/m101-verified): col = lane&31, row = (r&3)+8*(r>>2)+4*(lane>>5)
  if (EPI == 1) {
    #pragma unroll
    for (int bi = 0; bi < 2; ++bi)
      #pragma unroll
      for (int bj = 0; bj < 2; ++bj)
        #pragma unroll
        for (int r = 0; r < 16; ++r) {
          int m = m0 + wm*64 + bi*32 + (r & 3) + 8*(r >> 2) + 4*lg2;
          int n = n0 + wn*64 + bj*32 + l31;
          Of[(size_t)m*DMODEL + n] = acc[bi][bj][r];
        }
    return;
  }

  unsigned short* Odst = (z == 0) ? O0 : ((z == 1) ? O1 : O2);

  if (z == 2) {
    // V^T: acc -> LDS [n][m] (136-short padded rows), then coalesced stores
    unsigned short* tb = (unsigned short*)smem;          // 128 x 136
    #pragma unroll
    for (int bi = 0; bi < 2; ++bi)
      #pragma unroll
      for (int bj = 0; bj < 2; ++bj) {
        int n_loc = wn*64 + bj*32 + l31;
        #pragma unroll
        for (int g = 0; g < 4; ++g) {
          int m_loc = wm*64 + bi*32 + 8*g + 4*lg2;
          ushort4 pk;
          pk.x = f2bf(acc[bi][bj][g*4 + 0]);
          pk.y = f2bf(acc[bi][bj][g*4 + 1]);
          pk.z = f2bf(acc[bi][bj][g*4 + 2]);
          pk.w = f2bf(acc[bi][bj][g*4 + 3]);
          *(ushort4*)(tb + n_loc*136 + m_loc) = pk;
        }
      }
    __syncthreads();
    const int bb  = m0 >> 11;
    const int sq0 = m0 & (SEQ - 1);
    const size_t obase = (size_t)bb * NHEADS * DKH * SEQ;
    #pragma unroll
    for (int it = 0; it < 8; ++it) {
      int nn = it*16 + (tid >> 4);
      int cc = tid & 15;
      bf16x8 v8 = *(const bf16x8*)(tb + nn*136 + cc*8);
      int hh = (n0 + nn) >> 6;
      int dk = nn & 63;
      *(bf16x8*)&Odst[obase + ((size_t)hh*DKH + dk)*SEQ + sq0 + cc*8] = v8;
    }
  } else {
    float invf2[2];
    #pragma unroll
    for (int bj = 0; bj < 2; ++bj)
      invf2[bj] = exp2f(-0.41524101186092029f * (float)((bj*32 + l31) >> 1));
    #pragma unroll
    for (int bi = 0; bi < 2; ++bi)
      #pragma unroll
      for (int bj = 0; bj < 2; ++bj)
        #pragma unroll
        for (int r = 0; r < 16; ++r) {
          int m = m0 + wm*64 + bi*32 + (r & 3) + 8*(r >> 2) + 4*lg2;
          int n = n0 + wn*64 + bj*32 + l31;
          float v = acc[bi][bj][r];
          int b = m >> 11, sq = m & (SEQ-1), hh = n >> 6, dk = n & 63;
          float prt = __shfl_xor(v, 1);                  // RoPE pair
          float ang = (float)sq * invf2[bj];
          float sn, cs;
          __sincosf(ang, &sn, &cs);
          float out = (l31 & 1) ? (sn*prt + cs*v) : (cs*v - sn*prt);
          if (z == 0) out *= 0.18033688011112043f;       // (1/8) * log2(e)
          Odst[(((size_t)b*NHEADS + hh)*SEQ + sq)*DKH + dk] = f2bf(out);
        }
  }
}

// ---------------- causal flash attention: SWAPPED QK^T (lane-local rows) -------
// 1-D grid 512 (XCD-swizzled): block = pair of 128-row q-tiles {px, 15-px}.
// 8 waves x 16 q-rows. V supplied V^T. exp2-domain softmax, T13 lazy max.
// sc = mfma(K, Q) -> sc[nt][kr] = S[kv=kv0+nt*16+lg*4+kr][q=myrow0+li]: each
// lane owns one q-row -> softmax is lane-local; P packed to bf16 via
// v_cvt_pk_bf16_f32 and PV A-frags gathered in-register via shfl (no P-LDS).
// LDS = 32 KiB (K/V dbuf only).
__global__ __launch_bounds__(512)
void attn_kernel(const unsigned short* __restrict__ Qg,
                 const unsigned short* __restrict__ Kg,
                 const unsigned short* __restrict__ Vtg,
                 unsigned short* __restrict__ Og)
{
  const int lgid = (blockIdx.x & 7) * 64 + (blockIdx.x >> 3);
  const int px = lgid & 7;
  const int bh = lgid >> 3;
  const int tid = threadIdx.x;
  const int lane = tid & 63, w = tid >> 6;
  const int li = lane & 15, lg = lane >> 4;
  const float THRL2 = 11.0f;

  __shared__ unsigned short sK[2][64*64];
  __shared__ unsigned short sV[2][64*64];

  const size_t bhBase = (size_t)bh * SEQ * DKH;
  const f32x4 fz = {0.f, 0.f, 0.f, 0.f};

  auto STAGE = [&](int buf, int t) {
    const int kv0 = t * 64;
    int off16 = w*64 + lane;
    int r = off16 >> 3, p = off16 & 7;
    int s = p ^ (r & 7);
    gload_lds16(Kg  + bhBase + (size_t)(kv0 + r)*DKH + s*8, (char*)sK[buf] + w*1024);
    gload_lds16(Vtg + bhBase + (size_t)r*SEQ + kv0 + s*8,   (char*)sV[buf] + w*1024);
  };

  const int srcA = li + (((2*lg)     & 3) << 4);   // holder of kv4 = 2lg (+8kf)
  const int srcB = li + (((2*lg + 1) & 3) << 4);   // holder of kv4 = 2lg+1 (+8kf)
  const bool hi2 = (lg >= 2);

  #pragma unroll 1
  for (int pass = 0; pass < 2; ++pass) {
    const int qt = pass ? (15 - px) : px;
    const int q0 = qt * 128;
    const int myrow0 = q0 + w*16;
    const int qrow = myrow0 + li;      // this lane's q-row

    bf16x8 qf[2];
    {
      const unsigned short* qp = Qg + bhBase + (size_t)qrow*DKH + lg*8;
      qf[0] = *(const bf16x8*)qp;
      qf[1] = *(const bf16x8*)(qp + 32);
    }

    f32x4 acc_o[4];
    #pragma unroll
    for (int nt = 0; nt < 4; ++nt) acc_o[nt] = fz;
    float m_r = -1e30f;                // running max for q=qrow (log2 units)
    float ls  = 0.f;                   // running denom for q=qrow

    const int nt_stage = 2*qt + 2;
    const int last_t  = 2*qt + (w >= 4 ? 1 : 0);

    STAGE(0, 0);
    STAGE(1, 1);

    for (int t = 0; t < nt_stage; ++t) {
      const int cur = t & 1;
      if (t == nt_stage - 1) asm volatile("s_waitcnt vmcnt(0)" ::: "memory");
      else                   asm volatile("s_waitcnt vmcnt(2)" ::: "memory");
      __builtin_amdgcn_s_barrier();
      __builtin_amdgcn_sched_barrier(0);

      if (t <= last_t) {
        const int kv0 = t * 64;
        f32x4 sc[4];
        #pragma unroll
        for (int nt = 0; nt < 4; ++nt) sc[nt] = fz;
        __builtin_amdgcn_s_setprio(1);
        #pragma unroll
        for (int kf = 0; kf < 2; ++kf) {
          #pragma unroll
          for (int nt = 0; nt < 4; ++nt) {
            int row = nt*16 + li;
            int sp = (kf*4 + lg) ^ (row & 7);
            bf16x8 kb = *(const bf16x8*)(sK[cur] + row*64 + sp*8);
            sc[nt] = mfma16(kb, qf[kf], sc[nt]);   // SWAPPED: D[kv][q]
          }
        }
        __builtin_amdgcn_s_setprio(0);

        // causal mask: kv > q
        if (t == last_t) {
          #pragma unroll
          for (int nt = 0; nt < 4; ++nt)
            #pragma unroll
            for (int kr = 0; kr < 4; ++kr) {
              int kv = kv0 + nt*16 + lg*4 + kr;
              if (kv > qrow) sc[nt][kr] = -1e30f;
            }
        }

        // T13 lazy max (lane-local row chunk)
        float pm = sc[0][0];
        #pragma unroll
        for (int nt = 0; nt < 4; ++nt)
          #pragma unroll
          for (int kr = 0; kr < 4; ++kr)
            pm = fmaxf(pm, sc[nt][kr]);
        if (__any(pm > m_r + THRL2)) {
          float m2 = pm;
          m2 = fmaxf(m2, __shfl_xor(m2, 16));
          m2 = fmaxf(m2, __shfl_xor(m2, 32));
          float mn = fmaxf(m_r, m2);
          float scl = __builtin_amdgcn_exp2f(m_r - mn);
          m_r = mn;
          ls *= scl;
          float sclk[4];
          #pragma unroll
          for (int kr = 0; kr < 4; ++kr)
            sclk[kr] = __shfl(scl, lg*4 + kr);   // scl of acc_o's q-row
          #pragma unroll
          for (int nt = 0; nt < 4; ++nt)
            #pragma unroll
            for (int kr = 0; kr < 4; ++kr)
              acc_o[nt][kr] *= sclk[kr];
        }

        // exp2 + row-sum (lane-local, reduced across the 4 lg-lanes)
        float rs = 0.f;
        #pragma unroll
        for (int nt = 0; nt < 4; ++nt)
          #pragma unroll
          for (int kr = 0; kr < 4; ++kr) {
            float pv = __builtin_amdgcn_exp2f(sc[nt][kr] - m_r);
            sc[nt][kr] = pv;
            rs += pv;
          }
        rs += __shfl_xor(rs, 16);
        rs += __shfl_xor(rs, 32);
        ls += rs;

        // pack P to bf16 pairs: u[nt][j] = (kv base+2j, base+2j+1), base=nt*16+lg*4
        unsigned u00 = cvtpk_bf16(sc[0][0], sc[0][1]);
        unsigned u01 = cvtpk_bf16(sc[0][2], sc[0][3]);
        unsigned u10 = cvtpk_bf16(sc[1][0], sc[1][1]);
        unsigned u11 = cvtpk_bf16(sc[1][2], sc[1][3]);
        unsigned u20 = cvtpk_bf16(sc[2][0], sc[2][1]);
        unsigned u21 = cvtpk_bf16(sc[2][2], sc[2][3]);
        unsigned u30 = cvtpk_bf16(sc[3][0], sc[3][1]);
        unsigned u31 = cvtpk_bf16(sc[3][2], sc[3][3]);

        // gather pa[kf]: lane (li,lg) needs kv = kf*32 + lg*8 + 0..7
        unsigned a00 = __shfl(u00, srcA), a10 = __shfl(u10, srcA);
        unsigned a01 = __shfl(u01, srcA), a11 = __shfl(u11, srcA);
        unsigned b00 = __shfl(u00, srcB), b10 = __shfl(u10, srcB);
        unsigned b01 = __shfl(u01, srcB), b11 = __shfl(u11, srcB);
        bf16x8 pa0 = pack4(hi2 ? a10 : a00, hi2 ? a11 : a01,
                           hi2 ? b10 : b00, hi2 ? b11 : b01);
        unsigned c20 = __shfl(u20, srcA), c30 = __shfl(u30, srcA);
        unsigned c21 = __shfl(u21, srcA), c31 = __shfl(u31, srcA);
        unsigned d20 = __shfl(u20, srcB), d30 = __shfl(u30, srcB);
        unsigned d21 = __shfl(u21, srcB), d31 = __shfl(u31, srcB);
        bf16x8 pa1 = pack4(hi2 ? c30 : c20, hi2 ? c31 : c21,
                           hi2 ? d30 : d20, hi2 ? d31 : d21);

        // O += P * V (B-frag from V^T tile, unchanged)
        __builtin_amdgcn_s_setprio(1);
        #pragma unroll
        for (int nt = 0; nt < 4; ++nt) {
          int rr = nt*16 + li;
          int sp0 = (0*4 + lg) ^ (rr & 7);
          bf16x8 vb0 = *(const bf16x8*)(sV[cur] + rr*64 + sp0*8);
          acc_o[nt] = mfma16(pa0, vb0, acc_o[nt]);
        }
        #pragma unroll
        for (int nt = 0; nt < 4; ++nt) {
          int rr = nt*16 + li;
          int sp1 = (1*4 + lg) ^ (rr & 7);
          bf16x8 vb1 = *(const bf16x8*)(sV[cur] + rr*64 + sp1*8);
          acc_o[nt] = mfma16(pa1, vb1, acc_o[nt]);
        }
        __builtin_amdgcn_s_setprio(0);
      }

      __builtin_amdgcn_sched_barrier(0);
      __builtin_amdgcn_s_barrier();
      __builtin_amdgcn_sched_barrier(0);
      if (t + 2 < nt_stage) STAGE(cur, t + 2);
    }

    // epilogue: fetch denom of acc_o's q-rows, normalize, store
    const int b = bh >> 4, hh = bh & 15;
    #pragma unroll
    for (int kr = 0; kr < 4; ++kr) {
      float lsr = __shfl(ls, lg*4 + kr);
      float inv = __builtin_amdgcn_rcpf(lsr);
      int srow = myrow0 + lg*4 + kr;
      size_t orow = ((size_t)b*SEQ + srow)*DMODEL + (size_t)hh*DKH;
      #pragma unroll
      for (int nt = 0; nt < 4; ++nt)
        Og[orow + nt*16 + li] = f2bf(acc_o[nt][kr] * inv);
    }
  }
}

extern "C" void kernel_launch(void* const* d_in, const int* in_sizes, int n_in,
                              void* d_out, int out_size, void* d_ws, size_t ws_size,
                              hipStream_t stream)
{
  (void)in_sizes; (void)n_in; (void)out_size; (void)ws_size;
  const float* X  = (const float*)d_in[0];
  const float* Wq = (const float*)d_in[1];
  const float* Wk = (const float*)d_in[2];
  const float* Wv = (const float*)d_in[3];
  const float* Wo = (const float*)d_in[4];

  // d_ws budget: 40 MiB. Q/K bf16 scratch (32 MiB) lives inside d_out (33.5 MiB),
  // dead until the final out-projection overwrites it (stream-ordered).
  char* ws = (char*)d_ws;
  const size_t SZ_X = (size_t)8192 * 1024 * 2;   // 16 MiB (bf16)
  const size_t SZ_W = (size_t)1024 * 1024 * 2;   // 2 MiB  (bf16)
  unsigned short* Xb  = (unsigned short*)(ws);
  unsigned short* Wqb = (unsigned short*)(ws + SZ_X);
  unsigned short* Wkb = (unsigned short*)(ws + SZ_X + 1*SZ_W);
  unsigned short* Wvb = (unsigned short*)(ws + SZ_X + 2*SZ_W);
  unsigned short* Wob = (unsigned short*)(ws + SZ_X + 3*SZ_W);
  unsigned short* Vtb = (unsigned short*)(ws + SZ_X + 4*SZ_W);   // V^T, ..40 MiB
  unsigned short* Qb  = (unsigned short*)d_out;                  // 16 MiB scratch
  unsigned short* Kb  = Qb + (size_t)8192 * 1024;                // 16 MiB scratch
  unsigned short* Ob  = Xb;   // X dead after QKV projection

  cast_kernel<<<8192, 256, 0, stream>>>(X, Xb, 8388608/4);
  cast4_kernel<<<dim3(1024, 4), 256, 0, stream>>>(Wq, Wk, Wv, Wo,
                                                  Wqb, Wkb, Wvb, Wob, 1048576/4);

  gemm_bt<0><<<1536, 256, 0, stream>>>(Xb, Wqb, Wkb, Wvb, Qb, Kb, Vtb, nullptr);
  attn_kernel<<<512, 512, 0, stream>>>(Qb, Kb, Vtb, Ob);
  gemm_bt<1><<<512, 256, 0, stream>>>(Ob, Wob, nullptr, nullptr,
                                      nullptr, nullptr, nullptr,
                                      (float*)d_out);
}

// Round 18
// 166.046 us; speedup vs baseline: 1.0598x; 1.0598x over previous
//
#include <hip/hip_runtime.h>

#define SEQ     2048
#define DMODEL  1024
#define NHEADS  16
#define DKH     64
#define BATCH   4

typedef __bf16 bf16x8 __attribute__((ext_vector_type(8)));
typedef float  f32x4  __attribute__((ext_vector_type(4)));
typedef float  f32x16 __attribute__((ext_vector_type(16)));

static __device__ __forceinline__ unsigned short f2bf(float x) {
  unsigned int u = __float_as_uint(x);
  u += 0x7fffu + ((u >> 16) & 1u);
  return (unsigned short)(u >> 16);
}
static __device__ __forceinline__ float bf2f(unsigned short b) {
  return __uint_as_float(((unsigned int)b) << 16);
}
static __device__ __forceinline__ void gload_lds16(const void* g, void* lds) {
  __builtin_amdgcn_global_load_lds((const __attribute__((address_space(1))) void*)g,
                                   (__attribute__((address_space(3))) void*)lds,
                                   16, 0, 0);
}
static __device__ __forceinline__ f32x4 mfma16(bf16x8 a, bf16x8 b, f32x4 c) {
  return __builtin_amdgcn_mfma_f32_16x16x32_bf16(a, b, c, 0, 0, 0);
}
static __device__ __forceinline__ f32x16 mfma32(bf16x8 a, bf16x8 b, f32x16 c) {
  return __builtin_amdgcn_mfma_f32_32x32x16_bf16(a, b, c, 0, 0, 0);
}
static __device__ __forceinline__ unsigned cvtpk_bf16(float lo, float hi) {
  unsigned r;
  asm("v_cvt_pk_bf16_f32 %0, %1, %2" : "=v"(r) : "v"(lo), "v"(hi));
  return r;
}

// ---------------- fp32 -> bf16 cast ----------------
__global__ void cast_kernel(const float* __restrict__ src,
                            unsigned short* __restrict__ dst, int n4) {
  int i = blockIdx.x * 256 + threadIdx.x;
  if (i >= n4) return;
  float4 v = ((const float4*)src)[i];
  ushort4 o;
  o.x = f2bf(v.x); o.y = f2bf(v.y); o.z = f2bf(v.z); o.w = f2bf(v.w);
  ((ushort4*)dst)[i] = o;
}

// 4 weight matrices in one launch (blockIdx.y selects)
__global__ void cast4_kernel(const float* __restrict__ s0, const float* __restrict__ s1,
                             const float* __restrict__ s2, const float* __restrict__ s3,
                             unsigned short* __restrict__ d0, unsigned short* __restrict__ d1,
                             unsigned short* __restrict__ d2, unsigned short* __restrict__ d3,
                             int n4) {
  int i = blockIdx.x * 256 + threadIdx.x;
  if (i >= n4) return;
  const float* s = (blockIdx.y == 0) ? s0 : (blockIdx.y == 1) ? s1 : (blockIdx.y == 2) ? s2 : s3;
  unsigned short* d = (blockIdx.y == 0) ? d0 : (blockIdx.y == 1) ? d1 : (blockIdx.y == 2) ? d2 : d3;
  float4 v = ((const float4*)s)[i];
  ushort4 o;
  o.x = f2bf(v.x); o.y = f2bf(v.y); o.z = f2bf(v.z); o.w = f2bf(v.w);
  ((ushort4*)d)[i] = o;
}

// ---------------- GEMM (frozen round-16): 128x128, BK=64, dbuf vmcnt(8),
// 32x32x16 MFMA; V^T via LDS-transposed coalesced stores ----------------
template<int EPI>
__global__ __launch_bounds__(256)
void gemm_bt(const unsigned short* __restrict__ A,
             const unsigned short* __restrict__ W0,
             const unsigned short* __restrict__ W1,
             const unsigned short* __restrict__ W2,
             unsigned short* __restrict__ O0,
             unsigned short* __restrict__ O1,
             unsigned short* __restrict__ O2,
             float* __restrict__ Of)
{
  __shared__ unsigned short smem[4][128*64];   // [0..1]=A dbuf, [2..3]=B dbuf (64 KiB)
  const int tid = threadIdx.x;
  const int lane = tid & 63, w = tid >> 6;
  const int wm = w >> 1, wn = w & 1;
  const int l31 = lane & 31, lg2 = lane >> 5;

  const int NWG = (EPI == 0) ? 1536 : 512;
  const int CPX = NWG / 8;
  const int lgid = (blockIdx.x & 7) * CPX + (blockIdx.x >> 3);
  const int n0 = (lgid & 7) * 128;
  const int m0 = ((lgid >> 3) & 63) * 128;
  const int z  = (EPI == 0) ? (lgid >> 9) : 0;
  const unsigned short* Bw = (EPI == 0)
      ? ((z == 0) ? W0 : ((z == 1) ? W1 : W2)) : W0;

  f32x16 acc[2][2];
  #pragma unroll
  for (int a = 0; a < 2; ++a)
    #pragma unroll
    for (int b = 0; b < 2; ++b)
      #pragma unroll
      for (int r = 0; r < 16; ++r)
        acc[a][b][r] = 0.f;

  auto STAGE = [&](int buf, int t) {
    const int k0 = t * 64;
    #pragma unroll
    for (int it = 0; it < 4; ++it) {
      int c = it*4 + w;
      int off16 = c*64 + lane;
      int r = off16 >> 3, p = off16 & 7;
      int s = p ^ (r & 7);
      gload_lds16(A  + (size_t)(m0 + r)*DMODEL + k0 + s*8, (char*)smem[buf]     + c*1024);
      gload_lds16(Bw + (size_t)(n0 + r)*DMODEL + k0 + s*8, (char*)smem[2 + buf] + c*1024);
    }
  };

  const int NT = DMODEL / 64;
  STAGE(0, 0);
  STAGE(1, 1);

  for (int t = 0; t < NT; ++t) {
    const int cur = t & 1;
    if (t == NT - 1) asm volatile("s_waitcnt vmcnt(0)" ::: "memory");
    else             asm volatile("s_waitcnt vmcnt(8)" ::: "memory");
    __builtin_amdgcn_s_barrier();
    __builtin_amdgcn_sched_barrier(0);

    #pragma unroll
    for (int ks = 0; ks < 4; ++ks) {       // K-slices of 16 within BK=64
      bf16x8 af[2], bg[2];
      #pragma unroll
      for (int bi = 0; bi < 2; ++bi) {
        int row = wm*64 + bi*32 + l31;
        int sp = (ks*2 + lg2) ^ (row & 7);
        af[bi] = *(const bf16x8*)((const char*)smem[cur] + row*128 + sp*16);
      }
      #pragma unroll
      for (int bj = 0; bj < 2; ++bj) {
        int row = wn*64 + bj*32 + l31;
        int sp = (ks*2 + lg2) ^ (row & 7);
        bg[bj] = *(const bf16x8*)((const char*)smem[2 + cur] + row*128 + sp*16);
      }
      __builtin_amdgcn_s_setprio(1);
      #pragma unroll
      for (int bi = 0; bi < 2; ++bi)
        #pragma unroll
        for (int bj = 0; bj < 2; ++bj)
          acc[bi][bj] = mfma32(af[bi], bg[bj], acc[bi][bj]);
      __builtin_amdgcn_s_setprio(0);
    }

    __builtin_amdgcn_sched_barrier(0);
    __builtin_amdgcn_s_barrier();
    __builtin_amdgcn_sched_barrier(0);
    if (t + 2 < NT) STAGE(cur, t + 2);
  }

  // C/D layout (m74/m101-verified): col = lane&31, row = (r&3)+8*(r>>2)+4*(lane>>5)
  if (EPI == 1) {
    #pragma unroll
    for (int bi = 0; bi < 2; ++bi)
      #pragma unroll
      for (int bj = 0; bj < 2; ++bj)
        #pragma unroll
        for (int r = 0; r < 16; ++r) {
          int m = m0 + wm*64 + bi*32 + (r & 3) + 8*(r >> 2) + 4*lg2;
          int n = n0 + wn*64 + bj*32 + l31;
          Of[(size_t)m*DMODEL + n] = acc[bi][bj][r];
        }
    return;
  }

  unsigned short* Odst = (z == 0) ? O0 : ((z == 1) ? O1 : O2);

  if (z == 2) {
    // V^T: acc -> LDS [n][m] (136-short padded rows), then coalesced stores
    unsigned short* tb = (unsigned short*)smem;          // 128 x 136
    #pragma unroll
    for (int bi = 0; bi < 2; ++bi)
      #pragma unroll
      for (int bj = 0; bj < 2; ++bj) {
        int n_loc = wn*64 + bj*32 + l31;
        #pragma unroll
        for (int g = 0; g < 4; ++g) {
          int m_loc = wm*64 + bi*32 + 8*g + 4*lg2;
          ushort4 pk;
          pk.x = f2bf(acc[bi][bj][g*4 + 0]);
          pk.y = f2bf(acc[bi][bj][g*4 + 1]);
          pk.z = f2bf(acc[bi][bj][g*4 + 2]);
          pk.w = f2bf(acc[bi][bj][g*4 + 3]);
          *(ushort4*)(tb + n_loc*136 + m_loc) = pk;
        }
      }
    __syncthreads();
    const int bb  = m0 >> 11;
    const int sq0 = m0 & (SEQ - 1);
    const size_t obase = (size_t)bb * NHEADS * DKH * SEQ;
    #pragma unroll
    for (int it = 0; it < 8; ++it) {
      int nn = it*16 + (tid >> 4);
      int cc = tid & 15;
      bf16x8 v8 = *(const bf16x8*)(tb + nn*136 + cc*8);
      int hh = (n0 + nn) >> 6;
      int dk = nn & 63;
      *(bf16x8*)&Odst[obase + ((size_t)hh*DKH + dk)*SEQ + sq0 + cc*8] = v8;
    }
  } else {
    float invf2[2];
    #pragma unroll
    for (int bj = 0; bj < 2; ++bj)
      invf2[bj] = exp2f(-0.41524101186092029f * (float)((bj*32 + l31) >> 1));
    #pragma unroll
    for (int bi = 0; bi < 2; ++bi)
      #pragma unroll
      for (int bj = 0; bj < 2; ++bj)
        #pragma unroll
        for (int r = 0; r < 16; ++r) {
          int m = m0 + wm*64 + bi*32 + (r & 3) + 8*(r >> 2) + 4*lg2;
          int n = n0 + wn*64 + bj*32 + l31;
          float v = acc[bi][bj][r];
          int b = m >> 11, sq = m & (SEQ-1), hh = n >> 6, dk = n & 63;
          float prt = __shfl_xor(v, 1);                  // RoPE pair
          float ang = (float)sq * invf2[bj];
          float sn, cs;
          __sincosf(ang, &sn, &cs);
          float out = (l31 & 1) ? (sn*prt + cs*v) : (cs*v - sn*prt);
          if (z == 0) out *= 0.18033688011112043f;       // (1/8) * log2(e)
          Odst[(((size_t)b*NHEADS + hh)*SEQ + sq)*DKH + dk] = f2bf(out);
        }
  }
}

// ---------------- causal flash attention: swapped QK^T + cvt_pk P-LDS ---------
// 1-D grid 512 (XCD-swizzled): block = pair of 128-row q-tiles {px, 15-px}.
// 8 waves x 16 q-rows. V supplied V^T. exp2-domain softmax, T13 lazy max.
// sc = mfma(K, Q): lane (li,lg) holds S[kv=kv0+nt*16+lg*4+kr][q=myrow0+li]
// -> softmax lane-local; P packed via v_cvt_pk_bf16_f32 (kv runs are
// CONSECUTIVE per lane) and stored as 8B uint2 to per-wave P-LDS; PV A-frags
// read back 16B-aligned (round-16-proven read pattern).
__global__ __launch_bounds__(512)
void attn_kernel(const unsigned short* __restrict__ Qg,
                 const unsigned short* __restrict__ Kg,
                 const unsigned short* __restrict__ Vtg,
                 unsigned short* __restrict__ Og)
{
  const int lgid = (blockIdx.x & 7) * 64 + (blockIdx.x >> 3);
  const int px = lgid & 7;
  const int bh = lgid >> 3;
  const int tid = threadIdx.x;
  const int lane = tid & 63, w = tid >> 6;
  const int li = lane & 15, lg = lane >> 4;
  const float THRL2 = 11.0f;

  __shared__ unsigned short sK[2][64*64];
  __shared__ unsigned short sV[2][64*64];
  __shared__ unsigned short sP[8][16*72];    // per-wave P [q=li][kv], rows 72
  unsigned short* sPw = sP[w];

  const size_t bhBase = (size_t)bh * SEQ * DKH;
  const f32x4 fz = {0.f, 0.f, 0.f, 0.f};

  auto STAGE = [&](int buf, int t) {
    const int kv0 = t * 64;
    int off16 = w*64 + lane;
    int r = off16 >> 3, p = off16 & 7;
    int s = p ^ (r & 7);
    gload_lds16(Kg  + bhBase + (size_t)(kv0 + r)*DKH + s*8, (char*)sK[buf] + w*1024);
    gload_lds16(Vtg + bhBase + (size_t)r*SEQ + kv0 + s*8,   (char*)sV[buf] + w*1024);
  };

  #pragma unroll 1
  for (int pass = 0; pass < 2; ++pass) {
    const int qt = pass ? (15 - px) : px;
    const int q0 = qt * 128;
    const int myrow0 = q0 + w*16;
    const int qrow = myrow0 + li;      // this lane's q-row (softmax owner)

    bf16x8 qf[2];
    {
      const unsigned short* qp = Qg + bhBase + (size_t)qrow*DKH + lg*8;
      qf[0] = *(const bf16x8*)qp;
      qf[1] = *(const bf16x8*)(qp + 32);
    }

    f32x4 acc_o[4];
    #pragma unroll
    for (int nt = 0; nt < 4; ++nt) acc_o[nt] = fz;
    float m_r = -1e30f;                // running max for q=qrow (log2 units)
    float ls  = 0.f;                   // running denom for q=qrow

    const int nt_stage = 2*qt + 2;
    const int last_t  = 2*qt + (w >= 4 ? 1 : 0);

    STAGE(0, 0);
    STAGE(1, 1);

    for (int t = 0; t < nt_stage; ++t) {
      const int cur = t & 1;
      if (t == nt_stage - 1) asm volatile("s_waitcnt vmcnt(0)" ::: "memory");
      else                   asm volatile("s_waitcnt vmcnt(2)" ::: "memory");
      __builtin_amdgcn_s_barrier();
      __builtin_amdgcn_sched_barrier(0);

      if (t <= last_t) {
        const int kv0 = t * 64;
        f32x4 sc[4];
        #pragma unroll
        for (int nt = 0; nt < 4; ++nt) sc[nt] = fz;
        __builtin_amdgcn_s_setprio(1);
        #pragma unroll
        for (int kf = 0; kf < 2; ++kf) {
          #pragma unroll
          for (int nt = 0; nt < 4; ++nt) {
            int row = nt*16 + li;
            int sp = (kf*4 + lg) ^ (row & 7);
            bf16x8 kb = *(const bf16x8*)(sK[cur] + row*64 + sp*8);
            sc[nt] = mfma16(kb, qf[kf], sc[nt]);   // SWAPPED: D[kv][q]
          }
        }
        __builtin_amdgcn_s_setprio(0);

        // causal mask: kv > q
        if (t == last_t) {
          #pragma unroll
          for (int nt = 0; nt < 4; ++nt)
            #pragma unroll
            for (int kr = 0; kr < 4; ++kr) {
              int kv = kv0 + nt*16 + lg*4 + kr;
              if (kv > qrow) sc[nt][kr] = -1e30f;
            }
        }

        // T13 lazy max (lane-local 16-value chunk of row q=qrow)
        float pm = sc[0][0];
        #pragma unroll
        for (int nt = 0; nt < 4; ++nt)
          #pragma unroll
          for (int kr = 0; kr < 4; ++kr)
            pm = fmaxf(pm, sc[nt][kr]);
        if (__any(pm > m_r + THRL2)) {
          float m2 = pm;
          m2 = fmaxf(m2, __shfl_xor(m2, 16));
          m2 = fmaxf(m2, __shfl_xor(m2, 32));
          float mn = fmaxf(m_r, m2);
          float scl = __builtin_amdgcn_exp2f(m_r - mn);
          m_r = mn;
          ls *= scl;
          float sclk[4];
          #pragma unroll
          for (int kr = 0; kr < 4; ++kr)
            sclk[kr] = __shfl(scl, lg*4 + kr);   // scl of acc_o's q-row
          #pragma unroll
          for (int nt = 0; nt < 4; ++nt)
            #pragma unroll
            for (int kr = 0; kr < 4; ++kr)
              acc_o[nt][kr] *= sclk[kr];
        }

        // exp2 + partial row-sum (lane-local; full row = 4 lg-lanes)
        float rs = 0.f;
        #pragma unroll
        for (int nt = 0; nt < 4; ++nt)
          #pragma unroll
          for (int kr = 0; kr < 4; ++kr) {
            float pv = __builtin_amdgcn_exp2f(sc[nt][kr] - m_r);
            sc[nt][kr] = pv;
            rs += pv;
          }
        rs += __shfl_xor(rs, 16);
        rs += __shfl_xor(rs, 32);
        ls += rs;

        // P -> LDS: lane's 4 consecutive kv per nt -> 2 cvt_pk + 1 uint2 store
        #pragma unroll
        for (int nt = 0; nt < 4; ++nt) {
          uint2 pk;
          pk.x = cvtpk_bf16(sc[nt][0], sc[nt][1]);
          pk.y = cvtpk_bf16(sc[nt][2], sc[nt][3]);
          *(uint2*)(sPw + li*72 + nt*16 + lg*4) = pk;
        }

        // PV A-frags: q-row li, kv = kf*32 + lg*8 + 0..7 (same-wave RAW,
        // ordered by compiler-inserted lgkmcnt)
        bf16x8 pa0 = *(const bf16x8*)(sPw + li*72 + 0*32 + lg*8);
        bf16x8 pa1 = *(const bf16x8*)(sPw + li*72 + 1*32 + lg*8);

        // O += P * V (B-frag from V^T tile, round-16-proven pattern)
        __builtin_amdgcn_s_setprio(1);
        #pragma unroll
        for (int nt = 0; nt < 4; ++nt) {
          int rr = nt*16 + li;
          int sp0 = (0*4 + lg) ^ (rr & 7);
          bf16x8 vb0 = *(const bf16x8*)(sV[cur] + rr*64 + sp0*8);
          acc_o[nt] = mfma16(pa0, vb0, acc_o[nt]);
        }
        #pragma unroll
        for (int nt = 0; nt < 4; ++nt) {
          int rr = nt*16 + li;
          int sp1 = (1*4 + lg) ^ (rr & 7);
          bf16x8 vb1 = *(const bf16x8*)(sV[cur] + rr*64 + sp1*8);
          acc_o[nt] = mfma16(pa1, vb1, acc_o[nt]);
        }
        __builtin_amdgcn_s_setprio(0);
      }

      __builtin_amdgcn_sched_barrier(0);
      __builtin_amdgcn_s_barrier();
      __builtin_amdgcn_sched_barrier(0);
      if (t + 2 < nt_stage) STAGE(cur, t + 2);
    }

    // epilogue: fetch denom of acc_o's q-rows, normalize, store
    const int b = bh >> 4, hh = bh & 15;
    #pragma unroll
    for (int kr = 0; kr < 4; ++kr) {
      float lsr = __shfl(ls, lg*4 + kr);
      float inv = __builtin_amdgcn_rcpf(lsr);
      int srow = myrow0 + lg*4 + kr;
      size_t orow = ((size_t)b*SEQ + srow)*DMODEL + (size_t)hh*DKH;
      #pragma unroll
      for (int nt = 0; nt < 4; ++nt)
        Og[orow + nt*16 + li] = f2bf(acc_o[nt][kr] * inv);
    }
  }
}

extern "C" void kernel_launch(void* const* d_in, const int* in_sizes, int n_in,
                              void* d_out, int out_size, void* d_ws, size_t ws_size,
                              hipStream_t stream)
{
  (void)in_sizes; (void)n_in; (void)out_size; (void)ws_size;
  const float* X  = (const float*)d_in[0];
  const float* Wq = (const float*)d_in[1];
  const float* Wk = (const float*)d_in[2];
  const float* Wv = (const float*)d_in[3];
  const float* Wo = (const float*)d_in[4];

  // d_ws budget: 40 MiB. Q/K bf16 scratch (32 MiB) lives inside d_out (33.5 MiB),
  // dead until the final out-projection overwrites it (stream-ordered).
  char* ws = (char*)d_ws;
  const size_t SZ_X = (size_t)8192 * 1024 * 2;   // 16 MiB (bf16)
  const size_t SZ_W = (size_t)1024 * 1024 * 2;   // 2 MiB  (bf16)
  unsigned short* Xb  = (unsigned short*)(ws);
  unsigned short* Wqb = (unsigned short*)(ws + SZ_X);
  unsigned short* Wkb = (unsigned short*)(ws + SZ_X + 1*SZ_W);
  unsigned short* Wvb = (unsigned short*)(ws + SZ_X + 2*SZ_W);
  unsigned short* Wob = (unsigned short*)(ws + SZ_X + 3*SZ_W);
  unsigned short* Vtb = (unsigned short*)(ws + SZ_X + 4*SZ_W);   // V^T, ..40 MiB
  unsigned short* Qb  = (unsigned short*)d_out;                  // 16 MiB scratch
  unsigned short* Kb  = Qb + (size_t)8192 * 1024;                // 16 MiB scratch
  unsigned short* Ob  = Xb;   // X dead after QKV projection

  cast_kernel<<<8192, 256, 0, stream>>>(X, Xb, 8388608/4);
  cast4_kernel<<<dim3(1024, 4), 256, 0, stream>>>(Wq, Wk, Wv, Wo,
                                                  Wqb, Wkb, Wvb, Wob, 1048576/4);

  gemm_bt<0><<<1536, 256, 0, stream>>>(Xb, Wqb, Wkb, Wvb, Qb, Kb, Vtb, nullptr);
  attn_kernel<<<512, 512, 0, stream>>>(Qb, Kb, Vtb, Ob);
  gemm_bt<1><<<512, 256, 0, stream>>>(Ob, Wob, nullptr, nullptr,
                                      nullptr, nullptr, nullptr,
                                      (float*)d_out);
}